// Round 3
// baseline (359.209 us; speedup 1.0000x reference)
//
#include <hip/hip_runtime.h>
#include <hip/hip_bf16.h>

#define SDIM 2048
#define ADIM 4
#define LDIM 4
#define FDIM 64
#define KWIN 20
#define WWIN 41
#define CHUNK 64
#define NROWS (CHUNK + 2 * KWIN) /* 104 */
#define YPITCH 65                /* padded pitch, conflict-free */

// ws layout (fp32 elements):
#define WS_M 0
#define WS_WT 65536
#define WS_V 131072
#define WS_U 132096
#define WS_BT 133120
#define WS_C 134144

// ---- input dtype detector: per-wave, no sync needed ----
// Reads first 64 words of scale_tensor (N(0,1) data). If bf16, bits [14:7]
// of each word are a bf16 exponent field in [118,132] almost surely. If
// fp32, those bits are low mantissa bits (uniform) -> ~6% hit rate.
__device__ __forceinline__ int detect_is_bf16(const void* xp) {
  const unsigned* w = (const unsigned*)xp;
  const int lane = threadIdx.x & 63;
  const unsigned word = w[lane];
  const unsigned e = (word >> 7) & 0xFFu;
  const int hit = (e >= 118u && e <= 132u) ? 1 : 0;
  const unsigned long long m = __ballot(hit);
  return __popcll(m) >= 32;
}

__device__ __forceinline__ float ldf(const void* p, size_t i, int isbf) {
  return isbf ? __bfloat162float(((const __hip_bfloat16*)p)[i])
              : ((const float*)p)[i];
}

__global__ __launch_bounds__(1024) void prep_kernel(
    const void* __restrict__ x,
    const void* __restrict__ Wq, const void* __restrict__ bq,
    const void* __restrict__ Wk, const void* __restrict__ bk,
    const void* __restrict__ Wt, const void* __restrict__ bt,
    const int* __restrict__ sip, float* __restrict__ ws) {
  const int isbf = detect_is_bf16(x);
  const int al = blockIdx.x;          // a*4 + l
  const int a = al >> 2, li = al & 3;
  const int si = *sip;                // 4 by construction
  int off = 0;
  const int ATTR[5] = {3, 3, 1, 4, 3};
  for (int i = 0; i < si - 1 && i < 5; ++i) off += ATTR[i];  // 7
  const size_t wb = ((size_t)(off + a) * 5 + li) * 4096;
  const size_t bb = ((size_t)(off + a) * 5 + li) * 64;

  __shared__ float sq[4096];  // Wq[g][f]
  __shared__ float sk[4096];  // Wk[g][f]
  for (int i = threadIdx.x; i < 4096; i += 1024) {
    sq[i] = ldf(Wq, wb + i, isbf);
    sk[i] = ldf(Wk, wb + i, isbf);
  }
  __syncthreads();

  float* M = ws + WS_M + (size_t)al * 4096;
  float* Wtf = ws + WS_WT + (size_t)al * 4096;
  for (int i = threadIdx.x; i < 4096; i += 1024) {
    const int f = i >> 6, f2 = i & 63;
    float acc = 0.f;
    #pragma unroll 16
    for (int g = 0; g < 64; ++g) acc += sk[g * 64 + f] * sq[g * 64 + f2];
    M[i] = acc;                        // M[f][f2] = sum_g Wk[g,f]*Wq[g,f2]
    Wtf[i] = ldf(Wt, wb + i, isbf);    // Wt[g][f]
  }

  if (threadIdx.x < 64) {
    const int f = threadIdx.x;
    float v = 0.f, u = 0.f;
    for (int g = 0; g < 64; ++g) {
      const float bqg = ldf(bq, bb + g, isbf);
      const float bkg = ldf(bk, bb + g, isbf);
      v += sk[g * 64 + f] * bqg;   // v[f] = sum_g Wk[g,f]*bq[g]
      u += sq[g * 64 + f] * bkg;   // u[f] = sum_g Wq[g,f]*bk[g]
    }
    ws[WS_V + al * 64 + f] = v;
    ws[WS_U + al * 64 + f] = u;
    ws[WS_BT + al * 64 + f] = ldf(bt, bb + f, isbf);
    if (f == 0) {
      float c = 0.f;
      for (int g = 0; g < 64; ++g)
        c += ldf(bq, bb + g, isbf) * ldf(bk, bb + g, isbf);
      ws[WS_C + al] = c;
    }
  }
}

__global__ __launch_bounds__(256) void attn_kernel(
    const void* __restrict__ x, const float* __restrict__ ws,
    float* __restrict__ out) {
  const int isbf = detect_is_bf16(x);
  const int chunk = blockIdx.x;   // 0..31
  const int ba = blockIdx.y;      // b*4 + a
  const int b = ba >> 2, a = ba & 3;
  const int s0 = chunk * CHUNK;
  const int tid = threadIdx.x;
  const int lane = tid & 63;
  const int l = tid >> 6;         // wave id == level
  const int al = a * 4 + l;

  __shared__ float ybuf[NROWS * YPITCH];
  __shared__ float rowflag[NROWS];
  __shared__ float scratch[4][64];

  // ---- stage window rows: row r <-> j = s0 - 20 + r ----
  for (int r = tid >> 6; r < NROWS; r += 4) {
    const int j = s0 - KWIN + r;
    float yv = 0.f;
    if (j >= 0 && j < SDIM)
      yv = ldf(x, (((size_t)b * SDIM + j) * ADIM + a) * FDIM + lane, isbf);
    ybuf[r * YPITCH + lane] = yv;
    const unsigned long long nz = __ballot(yv != 0.f);
    if (lane == 0) rowflag[r] = (nz != 0ull) ? 1.f : 0.f;
  }
  __syncthreads();

  // ---- per-wave constants in registers ----
  float Mreg[64];   // M[lane][f2]
  float Wtreg[64];  // Wt[lane][f]
  const float* Mp = ws + WS_M + (size_t)al * 4096 + lane * 64;
  const float* Wp = ws + WS_WT + (size_t)al * 4096 + lane * 64;
  #pragma unroll
  for (int i = 0; i < 64; i += 4) {
    const float4 m4 = *(const float4*)(Mp + i);
    Mreg[i] = m4.x; Mreg[i + 1] = m4.y; Mreg[i + 2] = m4.z; Mreg[i + 3] = m4.w;
    const float4 w4 = *(const float4*)(Wp + i);
    Wtreg[i] = w4.x; Wtreg[i + 1] = w4.y; Wtreg[i + 2] = w4.z; Wtreg[i + 3] = w4.w;
  }
  const float vreg = ws[WS_V + al * 64 + lane];
  const float ureg = ws[WS_U + al * 64 + lane];
  const float btreg = ws[WS_BT + al * 64 + lane];
  const float creg = ws[WS_C + al];

  for (int sr = 0; sr < CHUNK; ++sr) {
    const int xrow = sr + KWIN;
    // ---- qk[lane] = v + M x ----
    float qk = vreg;
    #pragma unroll
    for (int f2 = 0; f2 < 64; ++f2) qk += Mreg[f2] * ybuf[xrow * YPITCH + f2];

    // ---- uxc = u.x + c  (butterfly reduce) ----
    float part = ureg * ybuf[xrow * YPITCH + lane];
    #pragma unroll
    for (int o = 32; o > 0; o >>= 1) part += __shfl_xor(part, o);
    const float uxc = part + creg;

    // ---- attn: lane w (0..40) ----
    scratch[l][lane] = qk;
    const int row = sr + lane;
    const int rc = row < NROWS ? row : NROWS - 1;
    float acc = 0.f;
    #pragma unroll
    for (int f = 0; f < 64; ++f) acc += scratch[l][f] * ybuf[rc * YPITCH + f];
    const bool ok = (lane < WWIN) && (rowflag[rc] > 0.5f);
    float attn = ok ? (acc + uxc) * 0.125f : -1.0e9f;

    // ---- softmax over 41 window lanes ----
    float mx = attn;
    #pragma unroll
    for (int o = 32; o > 0; o >>= 1) mx = fmaxf(mx, __shfl_xor(mx, o));
    float e = (lane < WWIN) ? __expf(attn - mx) : 0.f;
    float se = e;
    #pragma unroll
    for (int o = 32; o > 0; o >>= 1) se += __shfl_xor(se, o);
    const float wgt = e / se;

    // ---- ctx[lane] = sum_w wgt[w] * y[w][lane] ----
    scratch[l][lane] = wgt;
    float ctx = 0.f;
    #pragma unroll
    for (int w = 0; w < WWIN; ++w) ctx += scratch[l][w] * ybuf[(sr + w) * YPITCH + lane];

    // ---- out[lane] = bt + Wt ctx ----
    scratch[l][lane] = ctx;
    float o = btreg;
    #pragma unroll
    for (int f = 0; f < 64; ++f) o += Wtreg[f] * scratch[l][f];

    const size_t oidx =
        ((((size_t)b * SDIM + (s0 + sr)) * ADIM + a) * LDIM + l) * FDIM + lane;
    out[oidx] = o;
  }
}

extern "C" void kernel_launch(void* const* d_in, const int* in_sizes, int n_in,
                              void* d_out, int out_size, void* d_ws, size_t ws_size,
                              hipStream_t stream) {
  const void* x  = d_in[0];
  const void* Wq = d_in[1];
  const void* bq = d_in[2];
  const void* Wk = d_in[3];
  const void* bk = d_in[4];
  const void* Wt = d_in[5];
  const void* bt = d_in[6];
  const int* sip = (const int*)d_in[7];
  float* ws = (float*)d_ws;
  float* out = (float*)d_out;

  prep_kernel<<<16, 1024, 0, stream>>>(x, Wq, bq, Wk, bk, Wt, bt, sip, ws);
  attn_kernel<<<dim3(SDIM / CHUNK, 16), 256, 0, stream>>>(x, ws, out);
}

// Round 5
// 137.169 us; speedup vs baseline: 2.6187x; 2.6187x over previous
//
#include <hip/hip_runtime.h>
#include <hip/hip_bf16.h>

#define SDIM 2048
#define ADIM 4
#define KWIN 20
#define WWIN 41
#define CHUNK 64

typedef __attribute__((ext_vector_type(8))) short s8v;
typedef __attribute__((ext_vector_type(4))) float f32x4;
#define MFMA __builtin_amdgcn_mfma_f32_16x16x32_bf16

// ws layout: V fp32[16][64] @0; BT fp32[16][64] @4096; C fp32[16] @8192;
// MB bf16[16][80][64] @8256 (rows 0..63=M, 64=u, 65..79=0); WTB bf16[16][64][64] @172096
#define WSB_MB 8256
#define WSB_WT 172096

// LDS layout (50368 B) — no cross-wave writable overlap anywhere:
//  YJF/YFJ/RF: written before the single barrier, read-only after.
//  B1, CTX: wave mt touches only rows [16mt, 16mt+16).
#define O_YJF 0       /* bf16 [112][72] pitch 144 B */
#define O_YFJ 16128   /* bf16 [64][120] pitch 240 B */
#define O_B1  31488   /* bf16 [64][72]  QK then P   */
#define O_CTX 40704   /* bf16 [64][72]              */
#define O_RF  49920   /* fp32 [112] rowflag         */
#define LDS_TOTAL 50368

__device__ __forceinline__ int detect_is_bf16(const void* xp) {
  const unsigned* w = (const unsigned*)xp;
  const unsigned word = w[threadIdx.x & 63];
  const unsigned e = (word >> 7) & 0xFFu;
  const unsigned long long m = __ballot(e >= 118u && e <= 132u);
  return __popcll(m) >= 32;
}
__device__ __forceinline__ float ldf(const void* p, size_t i, int isbf) {
  return isbf ? __bfloat162float(((const __hip_bfloat16*)p)[i]) : ((const float*)p)[i];
}
__device__ __forceinline__ s8v ld8l(const char* p) { return *(const s8v*)p; }
__device__ __forceinline__ s8v ld8g(const short* p) { return *(const s8v*)p; }

__global__ __launch_bounds__(256) void prep_kernel(
    const void* __restrict__ x,
    const void* __restrict__ Wq, const void* __restrict__ bq,
    const void* __restrict__ Wk, const void* __restrict__ bk,
    const void* __restrict__ Wt, const void* __restrict__ bt,
    const int* __restrict__ sip, float* __restrict__ ws) {
  const int isbf = detect_is_bf16(x);
  const int al = blockIdx.x, a = al >> 2, li = al & 3;
  const int si = *sip;
  int off = 0;
  const int ATTR[5] = {3, 3, 1, 4, 3};
  for (int i = 0; i < si - 1 && i < 5; ++i) off += ATTR[i];
  const size_t wb = ((size_t)(off + a) * 5 + li) * 4096;
  const size_t bb = ((size_t)(off + a) * 5 + li) * 64;
  const int tid = threadIdx.x;

  __shared__ float sq[4096], sk[4096];
  __shared__ float sbq[64], sbk[64];
  for (int i = tid; i < 4096; i += 256) {
    sq[i] = ldf(Wq, wb + i, isbf);
    sk[i] = ldf(Wk, wb + i, isbf);
  }
  if (tid < 64) { sbq[tid] = ldf(bq, bb + tid, isbf); sbk[tid] = ldf(bk, bb + tid, isbf); }
  __syncthreads();

  __hip_bfloat16* mb  = (__hip_bfloat16*)((char*)ws + WSB_MB) + (size_t)al * 5120;
  __hip_bfloat16* wtb = (__hip_bfloat16*)((char*)ws + WSB_WT) + (size_t)al * 4096;

  for (int i = tid; i < 4096; i += 256) {
    const int f = i >> 6, f2 = i & 63;
    float acc = 0.f;
    #pragma unroll 16
    for (int g = 0; g < 64; ++g) acc += sk[g * 64 + f] * sq[g * 64 + f2];
    mb[f * 64 + f2] = __float2bfloat16(acc);            // M[n=f][k=f2]
    wtb[i] = __float2bfloat16(ldf(Wt, wb + i, isbf));   // Wt[g][f]
  }
  if (tid < 64) {
    float u = 0.f, v = 0.f;
    for (int g = 0; g < 64; ++g) {
      u += sq[g * 64 + tid] * sbk[g];
      v += sk[g * 64 + tid] * sbq[g];
    }
    mb[64 * 64 + tid] = __float2bfloat16(u);
    ws[al * 64 + tid] = v;
    ws[1024 + al * 64 + tid] = ldf(bt, bb + tid, isbf);
  }
  for (int i = tid; i < 15 * 64; i += 256) mb[65 * 64 + i] = __float2bfloat16(0.f);
  if (tid == 0) {
    float c = 0.f;
    for (int g = 0; g < 64; ++g) c += sbq[g] * sbk[g];
    ws[2048 + al] = c;
  }
}

__global__ __launch_bounds__(256) void attn_kernel(
    const void* __restrict__ x, const float* __restrict__ ws,
    float* __restrict__ out) {
  const int isbf = detect_is_bf16(x);
  const int chunk = blockIdx.x;          // 0..31
  const int ba = blockIdx.y;             // b*4 + a
  const int b = ba >> 2, a = ba & 3;
  const int s0 = chunk * CHUNK;
  const int tid = threadIdx.x;
  const int lane = tid & 63;
  const int mt = tid >> 6;               // wave id = 16-row m-tile
  const int c16 = lane & 15;
  const int q = lane >> 4;

  __shared__ __align__(16) char lds[LDS_TOTAL];

  // ---- stage window (both orientations, bf16) + rowflag; one barrier ----
  for (int r = mt; r < 112; r += 4) {
    const int j = s0 - KWIN + r;
    float yv = 0.f;
    if (r < 104 && j >= 0 && j < SDIM)
      yv = ldf(x, (((size_t)b * SDIM + j) * ADIM + a) * 64 + lane, isbf);
    const __hip_bfloat16 hv = __float2bfloat16(yv);
    *(__hip_bfloat16*)(lds + O_YJF + r * 144 + lane * 2) = hv;
    *(__hip_bfloat16*)(lds + O_YFJ + lane * 240 + r * 2) = hv;
    const unsigned long long nz = __ballot(yv != 0.f);
    if (lane == 0) ((float*)(lds + O_RF))[r] = nz ? 1.f : 0.f;
  }
  __syncthreads();

  const short* mbase  = (const short*)((const char*)ws + WSB_MB);
  const short* wtbase = (const short*)((const char*)ws + WSB_WT);

  // level-invariant: GEMM1 A-frag (query rows), rowflags for own band cols
  const char* xr = lds + O_YJF + (KWIN + 16 * mt + c16) * 144 + q * 16;
  const s8v xa0 = ld8l(xr), xa1 = ld8l(xr + 64);
  float rfv[4];
  #pragma unroll
  for (int nt = 0; nt < 4; ++nt)
    rfv[nt] = ((const float*)(lds + O_RF))[16 * mt + nt * 16 + c16];

  for (int l = 0; l < 4; ++l) {
    const int al = a * 4 + l;
    const short* mb  = mbase + (size_t)al * 5120;
    const short* wtb = wtbase + (size_t)al * 4096;
    const float c_al = ws[2048 + al];

    // ===== GEMM1: QK = X*M^T + v ; col tile nt=4 gives u.x =====
    f32x4 uacc;
    #pragma unroll
    for (int nt = 0; nt < 5; ++nt) {
      const int n = nt * 16 + c16;
      const s8v b0 = ld8g(mb + n * 64 + q * 8);
      const s8v b1 = ld8g(mb + n * 64 + 32 + q * 8);
      const float vv = (nt < 4) ? ws[al * 64 + n] : 0.f;
      f32x4 acc = {vv, vv, vv, vv};
      acc = MFMA(xa0, b0, acc, 0, 0, 0);
      acc = MFMA(xa1, b1, acc, 0, 0, 0);
      if (nt < 4) {
        #pragma unroll
        for (int r = 0; r < 4; ++r)
          *(__hip_bfloat16*)(lds + O_B1 + (16 * mt + 4 * q + r) * 144 + n * 2) =
              __float2bfloat16(acc[r]);
      } else {
        uacc = acc;   // col c16 of u-tile; only c16==0 lanes hold u.x
      }
    }
    float uxr[4];
    #pragma unroll
    for (int r = 0; r < 4; ++r) uxr[r] = __shfl(uacc[r], lane & 48) + c_al;
    __threadfence_block();  // QK stores -> cross-lane A-frag reads (same wave)

    // ===== GEMM2: S = QK * Y^T (band-local 64 cols), acc in registers =====
    const char* qrow = lds + O_B1 + (16 * mt + c16) * 144 + q * 16;
    const s8v qa0 = ld8l(qrow), qa1 = ld8l(qrow + 64);
    f32x4 sacc[4];
    #pragma unroll
    for (int nt = 0; nt < 4; ++nt) {
      const char* yr = lds + O_YJF + (16 * mt + nt * 16 + c16) * 144 + q * 16;
      const s8v b0 = ld8l(yr), b1 = ld8l(yr + 64);
      f32x4 s = {0.f, 0.f, 0.f, 0.f};
      s = MFMA(qa0, b0, s, 0, 0, 0);
      s = MFMA(qa1, b1, s, 0, 0, 0);
      sacc[nt] = s;
    }

    // ===== softmax in registers: rows 16mt+4q+r, cols nt*16+c16 =====
    float ee[4][4];
    float mx[4] = {-3.0e38f, -3.0e38f, -3.0e38f, -3.0e38f};
    #pragma unroll
    for (int nt = 0; nt < 4; ++nt) {
      const int jl = nt * 16 + c16;
      #pragma unroll
      for (int r = 0; r < 4; ++r) {
        const int w = jl - (4 * q + r);
        float lv = -1.0e9f;
        if (w >= 0 && w < WWIN && rfv[nt] != 0.f)
          lv = (sacc[nt][r] + uxr[r]) * 0.125f;
        ee[nt][r] = lv;
        mx[r] = fmaxf(mx[r], lv);
      }
    }
    #pragma unroll
    for (int r = 0; r < 4; ++r) {
      #pragma unroll
      for (int o = 1; o < 16; o <<= 1) mx[r] = fmaxf(mx[r], __shfl_xor(mx[r], o));
    }
    float se[4] = {0.f, 0.f, 0.f, 0.f};
    #pragma unroll
    for (int nt = 0; nt < 4; ++nt)
      #pragma unroll
      for (int r = 0; r < 4; ++r) {
        const float e = __expf(ee[nt][r] - mx[r]);
        ee[nt][r] = e;
        se[r] += e;
      }
    float rse[4];
    #pragma unroll
    for (int r = 0; r < 4; ++r) {
      #pragma unroll
      for (int o = 1; o < 16; o <<= 1) se[r] += __shfl_xor(se[r], o);
      rse[r] = 1.f / se[r];
    }
    #pragma unroll
    for (int nt = 0; nt < 4; ++nt)
      #pragma unroll
      for (int r = 0; r < 4; ++r)
        *(__hip_bfloat16*)(lds + O_B1 + (16 * mt + 4 * q + r) * 144 +
                           (nt * 16 + c16) * 2) = __float2bfloat16(ee[nt][r]);
    __threadfence_block();  // P stores -> cross-lane A-frag reads

    // ===== GEMM3: CTX = (P * Y) * rse =====
    const char* prow = lds + O_B1 + (16 * mt + c16) * 144 + q * 16;
    const s8v pa0 = ld8l(prow), pa1 = ld8l(prow + 64);
    #pragma unroll
    for (int nt = 0; nt < 4; ++nt) {
      const int f = nt * 16 + c16;
      const char* brow = lds + O_YFJ + f * 240 + 32 * mt + q * 16;
      const s8v b0 = ld8l(brow), b1 = ld8l(brow + 64);
      f32x4 cc = {0.f, 0.f, 0.f, 0.f};
      cc = MFMA(pa0, b0, cc, 0, 0, 0);
      cc = MFMA(pa1, b1, cc, 0, 0, 0);
      #pragma unroll
      for (int r = 0; r < 4; ++r)
        *(__hip_bfloat16*)(lds + O_CTX + (16 * mt + 4 * q + r) * 144 + f * 2) =
            __float2bfloat16(cc[r] * rse[r]);
    }
    __threadfence_block();  // CTX stores -> cross-lane A-frag reads

    // ===== GEMM4: OUT = CTX * Wt^T + bt =====
    const char* crow = lds + O_CTX + (16 * mt + c16) * 144 + q * 16;
    const s8v ca0 = ld8l(crow), ca1 = ld8l(crow + 64);
    #pragma unroll
    for (int nt = 0; nt < 4; ++nt) {
      const int g = nt * 16 + c16;
      const s8v b0 = ld8g(wtb + g * 64 + q * 8);
      const s8v b1 = ld8g(wtb + g * 64 + 32 + q * 8);
      f32x4 o = {0.f, 0.f, 0.f, 0.f};
      o = MFMA(ca0, b0, o, 0, 0, 0);
      o = MFMA(ca1, b1, o, 0, 0, 0);
      const float btv = ws[1024 + al * 64 + g];
      #pragma unroll
      for (int r = 0; r < 4; ++r) {
        const int row = 16 * mt + 4 * q + r;
        const size_t idx =
            (((size_t)b * SDIM + (s0 + row)) * ADIM + a) * 256 + l * 64 + g;
        out[idx] = o[r] + btv;
      }
    }
  }
}

extern "C" void kernel_launch(void* const* d_in, const int* in_sizes, int n_in,
                              void* d_out, int out_size, void* d_ws, size_t ws_size,
                              hipStream_t stream) {
  const void* x  = d_in[0];
  const void* Wq = d_in[1];
  const void* bq = d_in[2];
  const void* Wk = d_in[3];
  const void* bk = d_in[4];
  const void* Wt = d_in[5];
  const void* bt = d_in[6];
  const int* sip = (const int*)d_in[7];
  float* ws = (float*)d_ws;
  float* out = (float*)d_out;

  prep_kernel<<<16, 256, 0, stream>>>(x, Wq, bq, Wk, bk, Wt, bt, sip, ws);
  attn_kernel<<<dim3(SDIM / CHUNK, 16), 256, 0, stream>>>(x, ws, out);
}

// Round 6
// 118.717 us; speedup vs baseline: 3.0258x; 1.1554x over previous
//
#include <hip/hip_runtime.h>
#include <hip/hip_bf16.h>

#define SDIM 2048
#define KWIN 20
#define WWIN 41

typedef __attribute__((ext_vector_type(8))) short s8v;
typedef __attribute__((ext_vector_type(4))) float f32x4;
#define MFMA __builtin_amdgcn_mfma_f32_16x16x32_bf16

// ws: V fp32[16][64] @0; BT fp32[16][64] @4096(floats:1024); C fp32[16] @8192(2048);
// MB bf16[16][80][64] @8256 B; WTB bf16[16][64][64] @172096 B
#define WSB_MB 8256
#define WSB_WT 172096

// LDS: read-only after the single barrier. 31936 B -> 5 blocks/CU by LDS.
#define O_YJF 0       /* bf16 [112][72] pitch 144 B : Y[j][f] */
#define O_YFJ 16128   /* bf16 [64][120] pitch 240 B : Y^T[f][j] */
#define O_RF  31488   /* fp32 [112] rowflag */
#define LDS_TOTAL 31936

__device__ __forceinline__ int detect_is_bf16(const void* xp) {
  const unsigned* w = (const unsigned*)xp;
  const unsigned word = w[threadIdx.x & 63];
  const unsigned e = (word >> 7) & 0xFFu;
  const unsigned long long m = __ballot(e >= 118u && e <= 132u);
  return __popcll(m) >= 32;
}
__device__ __forceinline__ float ldf(const void* p, size_t i, int isbf) {
  return isbf ? __bfloat162float(((const __hip_bfloat16*)p)[i]) : ((const float*)p)[i];
}
// f32 -> bf16 bits, RNE (finite inputs only)
__device__ __forceinline__ unsigned bfb(float f) {
  union { float f; unsigned u; } x; x.f = f;
  return (x.u + 0x7FFFu + ((x.u >> 16) & 1u)) >> 16;
}
__device__ __forceinline__ int pkbf(float a, float b) {
  return (int)(bfb(a) | (bfb(b) << 16));
}
// C-layout tile pair (m in [0,32)) -> A/B-frag (k=8q+j) via quad shuffles.
// Source lane (c16,q') reg r holds Z[16t+4q'+r][c16]; p_t = {pk(r0,r1), pk(r2,r3)}.
__device__ __forceinline__ s8v xform(int p00, int p01, int p10, int p11, int lane) {
  const int q = lane >> 4;
  const int sA = (lane & 15) + ((q & 1) << 5);  // c16 + 16*(2*(q&1))
  const int sB = sA + 16;
  const bool hi = (q >> 1) != 0;
  const int w0a = __shfl(p00, sA), w0b = __shfl(p10, sA);
  const int w1a = __shfl(p01, sA), w1b = __shfl(p11, sA);
  const int w2a = __shfl(p00, sB), w2b = __shfl(p10, sB);
  const int w3a = __shfl(p01, sB), w3b = __shfl(p11, sB);
  union { int i[4]; s8v v; } u;
  u.i[0] = hi ? w0b : w0a;
  u.i[1] = hi ? w1b : w1a;
  u.i[2] = hi ? w2b : w2a;
  u.i[3] = hi ? w3b : w3a;
  return u.v;
}

__global__ __launch_bounds__(256) void prep_kernel(
    const void* __restrict__ x,
    const void* __restrict__ Wq, const void* __restrict__ bq,
    const void* __restrict__ Wk, const void* __restrict__ bk,
    const void* __restrict__ Wt, const void* __restrict__ bt,
    const int* __restrict__ sip, float* __restrict__ ws) {
  const int isbf = detect_is_bf16(x);
  const int al = blockIdx.x, a = al >> 2, li = al & 3;
  const int fq = blockIdx.y;  // f-quarter
  const int si = *sip;
  int off = 0;
  const int ATTR[5] = {3, 3, 1, 4, 3};
  for (int i = 0; i < si - 1 && i < 5; ++i) off += ATTR[i];
  const size_t wb = ((size_t)(off + a) * 5 + li) * 4096;
  const size_t bb = ((size_t)(off + a) * 5 + li) * 64;
  const int tid = threadIdx.x;

  __shared__ float sq[4096], sk[4096];
  __shared__ float sbq[64], sbk[64];
  for (int i = tid; i < 4096; i += 256) {
    sq[i] = ldf(Wq, wb + i, isbf);
    sk[i] = ldf(Wk, wb + i, isbf);
  }
  if (tid < 64) { sbq[tid] = ldf(bq, bb + tid, isbf); sbk[tid] = ldf(bk, bb + tid, isbf); }
  __syncthreads();

  __hip_bfloat16* mb  = (__hip_bfloat16*)((char*)ws + WSB_MB) + (size_t)al * 5120;
  __hip_bfloat16* wtb = (__hip_bfloat16*)((char*)ws + WSB_WT) + (size_t)al * 4096;

  for (int t = tid; t < 1024; t += 256) {
    const int f = fq * 16 + (t >> 6), f2 = t & 63;
    float acc = 0.f;
    #pragma unroll 16
    for (int g = 0; g < 64; ++g) acc += sk[g * 64 + f] * sq[g * 64 + f2];
    mb[f * 64 + f2] = __float2bfloat16(acc);                    // M[f][f2]
    wtb[f * 64 + f2] = __float2bfloat16(ldf(Wt, wb + f * 64 + f2, isbf));
  }
  if (fq == 0) {
    if (tid < 64) {
      float u = 0.f, v = 0.f;
      for (int g = 0; g < 64; ++g) {
        u += sq[g * 64 + tid] * sbk[g];
        v += sk[g * 64 + tid] * sbq[g];
      }
      mb[64 * 64 + tid] = __float2bfloat16(u);  // row 64 = u
      ws[al * 64 + tid] = v;
      ws[1024 + al * 64 + tid] = ldf(bt, bb + tid, isbf);
    }
    for (int i = tid; i < 15 * 64; i += 256) mb[65 * 64 + i] = __float2bfloat16(0.f);
    if (tid == 0) {
      float c = 0.f;
      for (int g = 0; g < 64; ++g) c += sbq[g] * sbk[g];
      ws[2048 + al] = c;
    }
  }
}

__global__ __launch_bounds__(256, 4) void attn_kernel(
    const void* __restrict__ x, const float* __restrict__ ws,
    float* __restrict__ out) {
  const int isbf = detect_is_bf16(x);
  const int chunk = blockIdx.x;   // 0..31
  const int ba = blockIdx.y;      // b*4 + a
  const int lp = blockIdx.z;      // level pair
  const int b = ba >> 2, a = ba & 3;
  const int s0 = chunk * 64;
  const int tid = threadIdx.x;
  const int lane = tid & 63;
  const int mt = tid >> 6;        // wave = 16-row m-tile
  const int c16 = lane & 15;
  const int q = lane >> 4;

  __shared__ __align__(16) char lds[LDS_TOTAL];

  // ---- stage Y window (both orientations) + rowflags; one barrier ----
  #pragma unroll
  for (int it = 0; it < 7; ++it) {
    const int r = it * 16 + (tid >> 4);   // 0..111
    const int j = s0 - KWIN + r;
    float4 yv = {0.f, 0.f, 0.f, 0.f};
    if (r < 104 && j >= 0 && j < SDIM) {
      if (isbf) {
        const size_t base = (((size_t)b * SDIM + j) * 4 + a) * 64 + c16 * 4;
        yv.x = ldf(x, base, 1); yv.y = ldf(x, base + 1, 1);
        yv.z = ldf(x, base + 2, 1); yv.w = ldf(x, base + 3, 1);
      } else {
        yv = *((const float4*)x + (((size_t)b * SDIM + j) * 4 + a) * 16 + c16);
      }
    }
    const int f0 = c16 * 4;
    ((int*)(lds + O_YJF + r * 144 + f0 * 2))[0] = pkbf(yv.x, yv.y);
    ((int*)(lds + O_YJF + r * 144 + f0 * 2))[1] = pkbf(yv.z, yv.w);
    *(unsigned short*)(lds + O_YFJ + (f0 + 0) * 240 + r * 2) = (unsigned short)bfb(yv.x);
    *(unsigned short*)(lds + O_YFJ + (f0 + 1) * 240 + r * 2) = (unsigned short)bfb(yv.y);
    *(unsigned short*)(lds + O_YFJ + (f0 + 2) * 240 + r * 2) = (unsigned short)bfb(yv.z);
    *(unsigned short*)(lds + O_YFJ + (f0 + 3) * 240 + r * 2) = (unsigned short)bfb(yv.w);
    const bool nz = (yv.x != 0.f) || (yv.y != 0.f) || (yv.z != 0.f) || (yv.w != 0.f);
    const unsigned long long m = __ballot(nz);
    if (c16 == 0) ((float*)(lds + O_RF))[r] = ((m >> (q * 16)) & 0xFFFFull) ? 1.f : 0.f;
  }
  __syncthreads();

  const short* mbase  = (const short*)((const char*)ws + WSB_MB);
  const short* wtbase = (const short*)((const char*)ws + WSB_WT);
  const char* yjf = lds + O_YJF;
  const char* yfj = lds + O_YFJ;

  // level-invariant: X^T B-frag (query rows), rowflags for own band
  const s8v xb0 = *(const s8v*)(yjf + (KWIN + 16 * mt + c16) * 144 + 16 * q);
  const s8v xb1 = *(const s8v*)(yjf + (KWIN + 16 * mt + c16) * 144 + 64 + 16 * q);
  float rfarr[16];
  #pragma unroll
  for (int nt = 0; nt < 4; ++nt) {
    const float4 t = *(const float4*)((const float*)(lds + O_RF) + 16 * mt + 16 * nt + 4 * q);
    rfarr[nt * 4 + 0] = t.x; rfarr[nt * 4 + 1] = t.y;
    rfarr[nt * 4 + 2] = t.z; rfarr[nt * 4 + 3] = t.w;
  }

  for (int li = 0; li < 2; ++li) {
    const int l = lp * 2 + li;
    const int al = a * 4 + l;
    const short* mb  = mbase + (size_t)al * 5120;
    const short* wtb = wtbase + (size_t)al * 4096;
    const float c_al = ws[2048 + al];

    // ===== G1 (swapped): QK^T = M * X^T (+v); m-tile 4 = u-row =====
    int pq[4][2];
    f32x4 uacc = {0.f, 0.f, 0.f, 0.f};
    #pragma unroll
    for (int nt = 0; nt < 5; ++nt) {
      const int rowm = (nt < 4) ? (16 * nt + c16) : (64 + c16);
      const s8v a0 = *(const s8v*)(mb + rowm * 64 + 8 * q);
      const s8v a1 = *(const s8v*)(mb + rowm * 64 + 32 + 8 * q);
      f32x4 acc;
      if (nt < 4) {
        const float4 v4 = *(const float4*)(ws + al * 64 + 16 * nt + 4 * q);
        acc[0] = v4.x; acc[1] = v4.y; acc[2] = v4.z; acc[3] = v4.w;
      } else {
        acc[0] = acc[1] = acc[2] = acc[3] = 0.f;
      }
      acc = MFMA(a0, xb0, acc, 0, 0, 0);
      acc = MFMA(a1, xb1, acc, 0, 0, 0);
      if (nt < 4) { pq[nt][0] = pkbf(acc[0], acc[1]); pq[nt][1] = pkbf(acc[2], acc[3]); }
      else uacc = acc;
    }
    const float ux = __shfl(uacc[0], lane & 15) + c_al;  // u.x for row=c16
    const s8v qb0 = xform(pq[0][0], pq[0][1], pq[1][0], pq[1][1], lane);
    const s8v qb1 = xform(pq[2][0], pq[2][1], pq[3][0], pq[3][1], lane);

    // ===== G2 (swapped): S^T = Y * QK^T ; D[j][row] =====
    f32x4 st[4];
    #pragma unroll
    for (int nt = 0; nt < 4; ++nt) {
      const char* yr = yjf + (16 * mt + 16 * nt + c16) * 144 + 16 * q;
      const s8v a0 = *(const s8v*)yr;
      const s8v a1 = *(const s8v*)(yr + 64);
      f32x4 s = {0.f, 0.f, 0.f, 0.f};
      s = MFMA(a0, qb0, s, 0, 0, 0);
      s = MFMA(a1, qb1, s, 0, 0, 0);
      st[nt] = s;
    }

    // ===== softmax in registers (row = c16, j spread over nt/q/r) =====
    float ee[16];
    float mx = -3.0e38f;
    #pragma unroll
    for (int nt = 0; nt < 4; ++nt)
      #pragma unroll
      for (int r = 0; r < 4; ++r) {
        const int w = 16 * nt + 4 * q + r - c16;
        float lv = -1.0e9f;
        if (w >= 0 && w < WWIN && rfarr[nt * 4 + r] != 0.f)
          lv = (st[nt][r] + ux) * 0.125f;
        ee[nt * 4 + r] = lv;
        mx = fmaxf(mx, lv);
      }
    mx = fmaxf(mx, __shfl_xor(mx, 16));
    mx = fmaxf(mx, __shfl_xor(mx, 32));
    float se = 0.f;
    #pragma unroll
    for (int i = 0; i < 16; ++i) { ee[i] = __expf(ee[i] - mx); se += ee[i]; }
    se += __shfl_xor(se, 16);
    se += __shfl_xor(se, 32);
    const float rse = 1.f / se;

    int pp[4][2];
    #pragma unroll
    for (int nt = 0; nt < 4; ++nt) {
      pp[nt][0] = pkbf(ee[nt * 4 + 0], ee[nt * 4 + 1]);
      pp[nt][1] = pkbf(ee[nt * 4 + 2], ee[nt * 4 + 3]);
    }
    const s8v pb0 = xform(pp[0][0], pp[0][1], pp[1][0], pp[1][1], lane);
    const s8v pb1 = xform(pp[2][0], pp[2][1], pp[3][0], pp[3][1], lane);

    // ===== G3 (swapped): CTX^T = Y^T * P ; scale by rse =====
    int cp[4][2];
    #pragma unroll
    for (int nt = 0; nt < 4; ++nt) {
      const char* fr = yfj + (16 * nt + c16) * 240 + 32 * mt + 16 * q;
      const s8v a0 = *(const s8v*)fr;
      const s8v a1 = *(const s8v*)(fr + 64);
      f32x4 cc = {0.f, 0.f, 0.f, 0.f};
      cc = MFMA(a0, pb0, cc, 0, 0, 0);
      cc = MFMA(a1, pb1, cc, 0, 0, 0);
      cp[nt][0] = pkbf(cc[0] * rse, cc[1] * rse);
      cp[nt][1] = pkbf(cc[2] * rse, cc[3] * rse);
    }
    const s8v cb0 = xform(cp[0][0], cp[0][1], cp[1][0], cp[1][1], lane);
    const s8v cb1 = xform(cp[2][0], cp[2][1], cp[3][0], cp[3][1], lane);

    // ===== G4 (swapped): OUT^T = Wt * CTX^T + bt ; coalesced dwordx4 store =====
    const int row = 16 * mt + c16;
    float* obase = out + ((((size_t)b * SDIM + s0 + row) * 4 + a) * 4 + l) * 64 + 4 * q;
    #pragma unroll
    for (int nt = 0; nt < 4; ++nt) {
      const s8v a0 = *(const s8v*)(wtb + (16 * nt + c16) * 64 + 8 * q);
      const s8v a1 = *(const s8v*)(wtb + (16 * nt + c16) * 64 + 32 + 8 * q);
      const float4 b4 = *(const float4*)(ws + 1024 + al * 64 + 16 * nt + 4 * q);
      f32x4 o;
      o[0] = b4.x; o[1] = b4.y; o[2] = b4.z; o[3] = b4.w;
      o = MFMA(a0, cb0, o, 0, 0, 0);
      o = MFMA(a1, cb1, o, 0, 0, 0);
      float4 o4; o4.x = o[0]; o4.y = o[1]; o4.z = o[2]; o4.w = o[3];
      *(float4*)(obase + 16 * nt) = o4;
    }
  }
}

extern "C" void kernel_launch(void* const* d_in, const int* in_sizes, int n_in,
                              void* d_out, int out_size, void* d_ws, size_t ws_size,
                              hipStream_t stream) {
  const void* x  = d_in[0];
  const void* Wq = d_in[1];
  const void* bq = d_in[2];
  const void* Wk = d_in[3];
  const void* bk = d_in[4];
  const void* Wt = d_in[5];
  const void* bt = d_in[6];
  const int* sip = (const int*)d_in[7];
  float* ws = (float*)d_ws;
  float* out = (float*)d_out;

  prep_kernel<<<dim3(16, 4), 256, 0, stream>>>(x, Wq, bq, Wk, bk, Wt, bt, sip, ws);
  attn_kernel<<<dim3(32, 16, 2), 256, 0, stream>>>(x, ws, out);
}